// Round 11
// baseline (217.884 us; speedup 1.0000x reference)
//
#include <hip/hip_runtime.h>

typedef unsigned short u16;
typedef __attribute__((ext_vector_type(4))) float f32x4;
typedef __attribute__((ext_vector_type(8))) short bf16x8;
typedef __attribute__((ext_vector_type(4))) unsigned short u16x4;

#define NT2 256         // K-tiles per block: 8 experts x 32 (BK=32)

__device__ __forceinline__ u16 f2bf(float f) {
  union { float f; unsigned u; } v; v.f = f;
  unsigned r = v.u + 0x7FFFu + ((v.u >> 16) & 1u);
  return (u16)(r >> 16);
}

__device__ __forceinline__ f32x4 zero4() {
  f32x4 z; z.x = 0.f; z.y = 0.f; z.z = 0.f; z.w = 0.f; return z;
}

// ---- kernel 1: x (f32) -> bf16 row-major ----
__global__ __launch_bounds__(256) void k_cvt_x(const float* __restrict__ x, u16* __restrict__ xb) {
  int i = blockIdx.x * 256 + threadIdx.x;
  f32x4 v = ((const f32x4*)x)[i];
  u16x4 o;
  o.x = f2bf(v.x); o.y = f2bf(v.y); o.z = f2bf(v.z); o.w = f2bf(v.w);
  ((u16x4*)xb)[i] = o;
}

// ---- kernel 2: W[m][k][n] f32 -> Wt[m][n][k] bf16 (64x64 LDS transpose, vectorized) ----
__global__ __launch_bounds__(256) void k_tw(const float* __restrict__ W, u16* __restrict__ wt) {
  __shared__ float t[64][65];
  int bid = blockIdx.x;
  int e = bid >> 8, rem = bid & 255, kt = rem >> 4, nt = rem & 15;
  int tid = threadIdx.x;
  // load: float4 per thread, 4 iters (64 rows x 16 float4-cols)
  int lr = tid >> 4, lc4 = (tid & 15) * 4;
  const float* src = W + (size_t)e * 1048576 + (size_t)(kt * 64) * 1024 + nt * 64;
  #pragma unroll
  for (int i = 0; i < 4; ++i) {
    int r = lr + i * 16;
    f32x4 v = *(const f32x4*)(src + (size_t)r * 1024 + lc4);
    t[r][lc4] = v.x; t[r][lc4 + 1] = v.y; t[r][lc4 + 2] = v.z; t[r][lc4 + 3] = v.w;
  }
  __syncthreads();
  // store: 8 bf16 (16B) per thread, 2 iters; dst row r2 (n-dir), 8 consecutive k
  int sr = tid >> 3, sc0 = (tid & 7) * 8;
  u16* dst = wt + (size_t)e * 1048576 + (size_t)(nt * 64) * 1024 + kt * 64;
  #pragma unroll
  for (int i = 0; i < 2; ++i) {
    int r2 = sr + i * 32;
    union { u16 u[8]; bf16x8 v; } o;
    #pragma unroll
    for (int j = 0; j < 8; ++j) o.u[j] = f2bf(t[sc0 + j][r2]);
    *(bf16x8*)(dst + (size_t)r2 * 1024 + sc0) = o.v;
  }
}

// ---- kernel 3: gates[b][m] = gu^2 / sum_m gu^2, gu = x@Wg + bg (f32x4 x-loads) ----
__global__ __launch_bounds__(256) void k_gates(const float* __restrict__ x, const float* __restrict__ Wg,
                                               const float* __restrict__ bg, float* __restrict__ gates) {
  int wid = threadIdx.x >> 6, lane = threadIdx.x & 63;
  int b = blockIdx.x * 4 + wid;
  const float* xr = x + (size_t)b * 1024;
  float acc[16];
  #pragma unroll
  for (int m = 0; m < 16; ++m) acc[m] = 0.f;
  for (int i0 = lane * 4; i0 < 1024; i0 += 256) {
    f32x4 xv = *(const f32x4*)(xr + i0);
    #pragma unroll
    for (int j = 0; j < 4; ++j) {
      float xs = xv[j];
      const f32x4* wg = (const f32x4*)(Wg + (size_t)(i0 + j) * 16);
      #pragma unroll
      for (int q = 0; q < 4; ++q) {
        f32x4 w = wg[q];
        acc[q*4+0] += xs * w.x; acc[q*4+1] += xs * w.y;
        acc[q*4+2] += xs * w.z; acc[q*4+3] += xs * w.w;
      }
    }
  }
  #pragma unroll
  for (int m = 0; m < 16; ++m) {
    #pragma unroll
    for (int off = 32; off > 0; off >>= 1)
      acc[m] += __shfl_xor(acc[m], off, 64);
  }
  float tot = 0.f, gp[16];
  #pragma unroll
  for (int m = 0; m < 16; ++m) { float gu = acc[m] + bg[m]; gp[m] = gu * gu; tot += gp[m]; }
  float inv = 1.f / tot;
  if (lane == 0) {
    #pragma unroll
    for (int m = 0; m < 16; ++m) gates[(size_t)b * 16 + m] = gp[m] * inv;
  }
}

// ---- kernel 4: fused MoE GEMM, 128x128 tile, BK=32, 3-buf counted-vmcnt, 2 blocks/CU ----
#define GLL(srcaddr, ldsaddr) \
  __builtin_amdgcn_global_load_lds((const __attribute__((address_space(1))) void*)(srcaddr), \
                                   (__attribute__((address_space(3))) void*)(ldsaddr), 16, 0, 0)

__global__ __launch_bounds__(256, 2)
void k_moe(const u16* __restrict__ xb, const u16* __restrict__ wt,
           const float* __restrict__ gates, const float* __restrict__ bias,
           float* __restrict__ out0, float* __restrict__ p1out) {
  __shared__ __align__(16) u16 sA[3 * 4096];    // 3 x 128x32 bf16 (8KB each)
  __shared__ __align__(16) u16 sB[3 * 4096];
  __shared__ float lgat[1024];                  // [8 experts][128 rows]
  __shared__ float lbias[1024];                 // [8 experts][128 cols]

  int tid = threadIdx.x;
  int bid = blockIdx.x;
  // R6 XCD swizzle: 64 consecutive swz per XCD -> 2 B-panels (4MB, L2-fit)
  int swz = (bid & 7) * 64 + (bid >> 3);
  int btile = swz & 31;
  int pnl = swz >> 5;          // 0..15
  int ntile = pnl & 7;
  int grp = pnl >> 3;
  int brow0 = btile * 128;
  int ncol0 = ntile * 128;
  int mb = grp * 8;

  int wid = tid >> 6, lane = tid & 63;
  int wm = wid >> 1, wn = wid & 1;              // 2M x 2N wave grid, wave tile 64x64
  int lrow = lane & 15, lk = lane >> 4;

  const u16* asrc = xb + (size_t)brow0 * 1024;
  const u16* bsrc = wt + (size_t)mb * 1048576 + (size_t)ncol0 * 1024;

  // stage offsets: 128x32 tile = 512 granules of 16B; 2 GLL per thread per matrix.
  // Row = 64B = 4 granules; swizzle: physical slot s holds logical granule s ^ ((r>>1)&3)
  // -> ds_read_b128 frag reads land 2-way on banks (free).
  int sg[2], ldd[2];
  #pragma unroll
  for (int it = 0; it < 2; ++it) {
    int idx = it * 256 + tid;
    int r = idx >> 2, s = idx & 3;
    sg[it] = r * 1024 + (s ^ ((r >> 1) & 3)) * 8;  // inverse-swizzled global src (elements)
    ldd[it] = (it * 256 + wid * 64) * 8;           // wave-uniform linear LDS dst (elements)
  }

  // frag read offsets: lane (lrow,lk) reads granule position lk ^ ((lrow>>1)&3) of its row
  int gsw = lk ^ ((lrow >> 1) & 3);
  int pa = (wm * 64 + lrow) * 32 + gsw * 8;
  int pb = (wn * 64 + lrow) * 32 + gsw * 8;

  f32x4 acc[4][4], oacc[4][4];
  #pragma unroll
  for (int i = 0; i < 4; ++i)
    #pragma unroll
    for (int j = 0; j < 4; ++j) { acc[i][j] = zero4(); oacc[i][j] = zero4(); }

  u16 *a0 = sA, *a1 = sA + 4096, *a2 = sA + 8192;
  u16 *b0 = sB, *b1 = sB + 4096, *b2 = sB + 8192;

  // ---- prologue: gates+bias -> LDS (full drain), then GLL t0,t1 with counted wait ----
  #pragma unroll
  for (int i = 0; i < 4; ++i) {
    int idx = i * 256 + tid;
    lgat[idx] = gates[(size_t)(brow0 + (idx & 127)) * 16 + mb + (idx >> 7)];
    lbias[idx] = bias[(size_t)(mb + (idx >> 7)) * 1024 + ncol0 + (idx & 127)];
  }
  __syncthreads();
  GLL(asrc + sg[0], a0 + ldd[0]); GLL(asrc + sg[1], a0 + ldd[1]);
  GLL(bsrc + sg[0], b0 + ldd[0]); GLL(bsrc + sg[1], b0 + ldd[1]);
  GLL(asrc + 32 + sg[0], a1 + ldd[0]); GLL(asrc + 32 + sg[1], a1 + ldd[1]);
  GLL(bsrc + 32 + sg[0], b1 + ldd[0]); GLL(bsrc + 32 + sg[1], b1 + ldd[1]);
  asm volatile("s_waitcnt vmcnt(4)" ::: "memory");   // t0 complete, t1 in flight
  __builtin_amdgcn_s_barrier();
  __builtin_amdgcn_sched_barrier(0);

  for (int t = 0; t < NT2; ++t) {
    bf16x8 af0, af1, af2, af3, bf0, bf1, bf2, bf3;
    af0 = *(const bf16x8*)&a0[pa];
    af1 = *(const bf16x8*)&a0[pa + 512];
    af2 = *(const bf16x8*)&a0[pa + 1024];
    af3 = *(const bf16x8*)&a0[pa + 1536];
    bf0 = *(const bf16x8*)&b0[pb];
    bf1 = *(const bf16x8*)&b0[pb + 512];
    bf2 = *(const bf16x8*)&b0[pb + 1024];
    bf3 = *(const bf16x8*)&b0[pb + 1536];

    if (t + 2 < NT2) {
      int t2 = t + 2;
      const u16* sa2 = asrc + (t2 & 31) * 32;
      const u16* sb2 = bsrc + (size_t)(t2 >> 5) * 1048576 + (t2 & 31) * 32;
      GLL(sa2 + sg[0], a2 + ldd[0]); GLL(sa2 + sg[1], a2 + ldd[1]);
      GLL(sb2 + sg[0], b2 + ldd[0]); GLL(sb2 + sg[1], b2 + ldd[1]);
    }

    __builtin_amdgcn_s_setprio(1);
    #pragma unroll
    for (int ni = 0; ni < 4; ++ni) {
      bf16x8 bv = (ni == 0) ? bf0 : (ni == 1) ? bf1 : (ni == 2) ? bf2 : bf3;
      acc[0][ni] = __builtin_amdgcn_mfma_f32_16x16x32_bf16(af0, bv, acc[0][ni], 0, 0, 0);
      acc[1][ni] = __builtin_amdgcn_mfma_f32_16x16x32_bf16(af1, bv, acc[1][ni], 0, 0, 0);
      acc[2][ni] = __builtin_amdgcn_mfma_f32_16x16x32_bf16(af2, bv, acc[2][ni], 0, 0, 0);
      acc[3][ni] = __builtin_amdgcn_mfma_f32_16x16x32_bf16(af3, bv, acc[3][ni], 0, 0, 0);
    }
    __builtin_amdgcn_s_setprio(0);

    // expert boundary: relu + bias + gate into running oacc
    if ((t & 31) == 31) {
      int ml = t >> 5;
      float bvv[4];
      #pragma unroll
      for (int ni = 0; ni < 4; ++ni) bvv[ni] = lbias[ml * 128 + wn * 64 + ni * 16 + lrow];
      #pragma unroll
      for (int mi = 0; mi < 4; ++mi) {
        f32x4 gv = *(const f32x4*)&lgat[ml * 128 + wm * 64 + mi * 16 + lk * 4];
        #pragma unroll
        for (int ni = 0; ni < 4; ++ni) {
          #pragma unroll
          for (int j = 0; j < 4; ++j) {
            float h = acc[mi][ni][j] + bvv[ni];
            h = fmaxf(h, 0.f);
            oacc[mi][ni][j] += gv[j] * h;
          }
          acc[mi][ni] = zero4();
        }
      }
    }

    // counted vmcnt: drain t+1's 4 GLLs, keep t+2's 4 in flight
    if (t < NT2 - 2)       asm volatile("s_waitcnt vmcnt(4)" ::: "memory");
    else if (t == NT2 - 2) asm volatile("s_waitcnt vmcnt(0)" ::: "memory");
    if (t < NT2 - 1) {
      __builtin_amdgcn_s_barrier();
      __builtin_amdgcn_sched_barrier(0);
      u16* ta = a0; a0 = a1; a1 = a2; a2 = ta;
      u16* tb = b0; b0 = b1; b1 = b2; b2 = tb;
    }
  }

  float* op = grp ? p1out : out0;
  #pragma unroll
  for (int mi = 0; mi < 4; ++mi)
    #pragma unroll
    for (int j = 0; j < 4; ++j) {
      int row = brow0 + wm * 64 + mi * 16 + lk * 4 + j;
      #pragma unroll
      for (int ni = 0; ni < 4; ++ni) {
        int col = ncol0 + wn * 64 + ni * 16 + lrow;
        op[(size_t)row * 1024 + col] = oacc[mi][ni][j];
      }
    }
}

// ---- kernel 5: out += p1 ----
__global__ __launch_bounds__(256) void k_add(float* __restrict__ out, const float* __restrict__ p1) {
  int i = blockIdx.x * 256 + threadIdx.x;
  f32x4 a = ((const f32x4*)out)[i];
  f32x4 b = ((const f32x4*)p1)[i];
  ((f32x4*)out)[i] = a + b;
}

extern "C" void kernel_launch(void* const* d_in, const int* in_sizes, int n_in,
                              void* d_out, int out_size, void* d_ws, size_t ws_size,
                              hipStream_t stream) {
  const float* x  = (const float*)d_in[0];   // [4096][1024]
  const float* W  = (const float*)d_in[1];   // [16][1024][1024]
  const float* b  = (const float*)d_in[2];   // [16][1024]
  const float* Wg = (const float*)d_in[3];   // [1024][16]
  const float* bg = (const float*)d_in[4];   // [16]
  float* out = (float*)d_out;                // [4096][1024]

  char* ws = (char*)d_ws;
  u16* xb     = (u16*)ws;                      // 8,388,608 B (row-major bf16)
  u16* wt     = (u16*)(ws + 8388608);          // 33,554,432 B
  float* gts  = (float*)(ws + 41943040);       // 262,144 B
  float* p1   = (float*)(ws + 42205184);       // 16,777,216 B

  k_cvt_x<<<4096, 256, 0, stream>>>(x, xb);
  k_tw<<<4096, 256, 0, stream>>>(W, wt);
  k_gates<<<1024, 256, 0, stream>>>(x, Wg, bg, gts);
  k_moe<<<512, 256, 0, stream>>>(xb, wt, gts, b, out, p1);
  k_add<<<4096, 256, 0, stream>>>(out, p1);
}

// Round 12
// 201.448 us; speedup vs baseline: 1.0816x; 1.0816x over previous
//
#include <hip/hip_runtime.h>

typedef unsigned short u16;
typedef __attribute__((ext_vector_type(4))) float f32x4;
typedef __attribute__((ext_vector_type(8))) short bf16x8;
typedef __attribute__((ext_vector_type(4))) unsigned short u16x4;

#define NT 128          // K-tiles per block: 8 experts x 16 (BK=64)

__device__ __forceinline__ u16 f2bf(float f) {
  union { float f; unsigned u; } v; v.f = f;
  unsigned r = v.u + 0x7FFFu + ((v.u >> 16) & 1u);
  return (u16)(r >> 16);
}

__device__ __forceinline__ f32x4 zero4() {
  f32x4 z; z.x = 0.f; z.y = 0.f; z.z = 0.f; z.w = 0.f; return z;
}

// ---- kernel 1: x (f32) -> bf16 row-major ----
__global__ __launch_bounds__(256) void k_cvt_x(const float* __restrict__ x, u16* __restrict__ xb) {
  int i = blockIdx.x * 256 + threadIdx.x;
  f32x4 v = ((const f32x4*)x)[i];
  u16x4 o;
  o.x = f2bf(v.x); o.y = f2bf(v.y); o.z = f2bf(v.z); o.w = f2bf(v.w);
  ((u16x4*)xb)[i] = o;
}

// ---- kernel 2: W[m][k][n] f32 -> Wt[m][n][k] bf16 (64x64 LDS transpose, vectorized) ----
__global__ __launch_bounds__(256) void k_tw(const float* __restrict__ W, u16* __restrict__ wt) {
  __shared__ float t[64][65];
  int bid = blockIdx.x;
  int e = bid >> 8, rem = bid & 255, kt = rem >> 4, nt = rem & 15;
  int tid = threadIdx.x;
  int lr = tid >> 4, lc4 = (tid & 15) * 4;
  const float* src = W + (size_t)e * 1048576 + (size_t)(kt * 64) * 1024 + nt * 64;
  #pragma unroll
  for (int i = 0; i < 4; ++i) {
    int r = lr + i * 16;
    f32x4 v = *(const f32x4*)(src + (size_t)r * 1024 + lc4);
    t[r][lc4] = v.x; t[r][lc4 + 1] = v.y; t[r][lc4 + 2] = v.z; t[r][lc4 + 3] = v.w;
  }
  __syncthreads();
  int sr = tid >> 3, sc0 = (tid & 7) * 8;
  u16* dst = wt + (size_t)e * 1048576 + (size_t)(nt * 64) * 1024 + kt * 64;
  #pragma unroll
  for (int i = 0; i < 2; ++i) {
    int r2 = sr + i * 32;
    union { u16 u[8]; bf16x8 v; } o;
    #pragma unroll
    for (int j = 0; j < 8; ++j) o.u[j] = f2bf(t[sc0 + j][r2]);
    *(bf16x8*)(dst + (size_t)r2 * 1024 + sc0) = o.v;
  }
}

// ---- kernel 3: gates[b][m] = gu^2 / sum_m gu^2, gu = x@Wg + bg ----
__global__ __launch_bounds__(256) void k_gates(const float* __restrict__ x, const float* __restrict__ Wg,
                                               const float* __restrict__ bg, float* __restrict__ gates) {
  int wid = threadIdx.x >> 6, lane = threadIdx.x & 63;
  int b = blockIdx.x * 4 + wid;
  const float* xr = x + (size_t)b * 1024;
  float acc[16];
  #pragma unroll
  for (int m = 0; m < 16; ++m) acc[m] = 0.f;
  for (int i0 = lane * 4; i0 < 1024; i0 += 256) {
    f32x4 xv = *(const f32x4*)(xr + i0);
    #pragma unroll
    for (int j = 0; j < 4; ++j) {
      float xs = xv[j];
      const f32x4* wg = (const f32x4*)(Wg + (size_t)(i0 + j) * 16);
      #pragma unroll
      for (int q = 0; q < 4; ++q) {
        f32x4 w = wg[q];
        acc[q*4+0] += xs * w.x; acc[q*4+1] += xs * w.y;
        acc[q*4+2] += xs * w.z; acc[q*4+3] += xs * w.w;
      }
    }
  }
  #pragma unroll
  for (int m = 0; m < 16; ++m) {
    #pragma unroll
    for (int off = 32; off > 0; off >>= 1)
      acc[m] += __shfl_xor(acc[m], off, 64);
  }
  float tot = 0.f, gp[16];
  #pragma unroll
  for (int m = 0; m < 16; ++m) { float gu = acc[m] + bg[m]; gp[m] = gu * gu; tot += gp[m]; }
  float inv = 1.f / tot;
  if (lane == 0) {
    #pragma unroll
    for (int m = 0; m < 16; ++m) gates[(size_t)b * 16 + m] = gp[m] * inv;
  }
}

// ---- kernel 4: fused MoE GEMM, 256x128 block, 8 waves, wave-tile 128x32, 3-buf vmcnt(6) ----
#define GLL(srcaddr, ldsaddr) \
  __builtin_amdgcn_global_load_lds((const __attribute__((address_space(1))) void*)(srcaddr), \
                                   (__attribute__((address_space(3))) void*)(ldsaddr), 16, 0, 0)

__global__ __launch_bounds__(512, 2)
void k_moe(const u16* __restrict__ xb, const u16* __restrict__ wt,
           const float* __restrict__ gates, const float* __restrict__ bias,
           float* __restrict__ out0, float* __restrict__ p1out) {
  __shared__ __align__(16) u16 sA[3 * 16384];   // 3 x 256x64 bf16 (32KB each)
  __shared__ __align__(16) u16 sB[3 * 8192];    // 3 x 128x64 bf16 (16KB each)
  __shared__ float lgat[2048];                  // [8 experts][256 rows]
  __shared__ float lbias[1024];                 // [8 experts][128 cols]

  int tid = threadIdx.x;
  int bid = blockIdx.x;
  // R6-style XCD panel grouping: XCD x owns 32 consecutive swz = 2 panels x 16 btiles.
  // Per-XCD B slice = 2 x 2MB (L2-fit); A spans xb (L3-resident, GLL-tolerant).
  int swz = (bid & 7) * 32 + (bid >> 3);
  int btile = swz & 15;        // 16 row tiles of 256
  int pnl = swz >> 4;          // 0..15
  int ntile = pnl & 7;         // 8 col tiles of 128
  int grp = pnl >> 3;          // 2 expert groups
  int brow0 = btile * 256;
  int ncol0 = ntile * 128;
  int mb = grp * 8;

  int wid = tid >> 6, lane = tid & 63;
  int wm = wid >> 2, wn = wid & 3;              // 2M x 4N wave grid, wave tile 128x32
  int lrow = lane & 15, lk = lane >> 4;
  int sw = lrow & 7;

  const u16* asrc = xb + (size_t)brow0 * 1024;
  const u16* bsrc = wt + (size_t)mb * 1048576 + (size_t)ncol0 * 1024;

  // stage offsets (16B granules, row = 8 granules, inverse-swizzle slot s^(r&7))
  int sgA[4], ldA[4], sgB[2], ldB[2];
  #pragma unroll
  for (int it = 0; it < 4; ++it) {
    int idx = it * 512 + tid;                   // 2048 granules: 256 rows x 8
    int r = idx >> 3, s = idx & 7;
    sgA[it] = r * 1024 + (s ^ (r & 7)) * 8;
    ldA[it] = (it * 512 + wid * 64) * 8;
  }
  #pragma unroll
  for (int it = 0; it < 2; ++it) {
    int idx = it * 512 + tid;                   // 1024 granules: 128 rows x 8
    int r = idx >> 3, s = idx & 7;
    sgB[it] = r * 1024 + (s ^ (r & 7)) * 8;
    ldB[it] = (it * 512 + wid * 64) * 8;
  }

  // frag row offsets (elements; row stride 64)
  int ra[8], rb[2];
  #pragma unroll
  for (int mi = 0; mi < 8; ++mi) ra[mi] = (wm * 128 + mi * 16 + lrow) * 64;
  #pragma unroll
  for (int ni = 0; ni < 2; ++ni) rb[ni] = (wn * 32 + ni * 16 + lrow) * 64;
  int pk0 = ((0 + lk) ^ sw) * 8;   // kk=0 granule slot
  int pk1 = ((4 + lk) ^ sw) * 8;   // kk=1

  f32x4 acc[8][2], oacc[8][2];
  #pragma unroll
  for (int i = 0; i < 8; ++i)
    #pragma unroll
    for (int j = 0; j < 2; ++j) { acc[i][j] = zero4(); oacc[i][j] = zero4(); }

  u16 *a0 = sA, *a1 = sA + 16384, *a2 = sA + 32768;
  u16 *b0 = sB, *b1 = sB + 8192, *b2 = sB + 16384;

  // ---- prologue: gates+bias -> LDS; GLL tiles 0,1; counted wait ----
  #pragma unroll
  for (int i = 0; i < 4; ++i) {
    int idx = i * 512 + tid;
    lgat[idx] = gates[(size_t)(brow0 + (idx & 255)) * 16 + mb + (idx >> 8)];
  }
  #pragma unroll
  for (int i = 0; i < 2; ++i) {
    int idx = i * 512 + tid;
    lbias[idx] = bias[(size_t)(mb + (idx >> 7)) * 1024 + ncol0 + (idx & 127)];
  }
  __syncthreads();
  GLL(asrc + sgA[0], a0 + ldA[0]); GLL(asrc + sgA[1], a0 + ldA[1]);
  GLL(asrc + sgA[2], a0 + ldA[2]); GLL(asrc + sgA[3], a0 + ldA[3]);
  GLL(bsrc + sgB[0], b0 + ldB[0]); GLL(bsrc + sgB[1], b0 + ldB[1]);
  GLL(asrc + 64 + sgA[0], a1 + ldA[0]); GLL(asrc + 64 + sgA[1], a1 + ldA[1]);
  GLL(asrc + 64 + sgA[2], a1 + ldA[2]); GLL(asrc + 64 + sgA[3], a1 + ldA[3]);
  GLL(bsrc + 64 + sgB[0], b1 + ldB[0]); GLL(bsrc + 64 + sgB[1], b1 + ldB[1]);
  asm volatile("s_waitcnt vmcnt(6)" ::: "memory");   // tile 0 resident; tile 1 in flight
  __builtin_amdgcn_s_barrier();
  __builtin_amdgcn_sched_barrier(0);

  for (int t = 0; t < NT; ++t) {
    // ---- kk = 0 ----
    bf16x8 af[8], bf0, bf1;
    #pragma unroll
    for (int mi = 0; mi < 8; ++mi) af[mi] = *(const bf16x8*)&a0[ra[mi] + pk0];
    bf0 = *(const bf16x8*)&b0[rb[0] + pk0];
    bf1 = *(const bf16x8*)&b0[rb[1] + pk0];

    if (t + 2 < NT) {
      int t2 = t + 2;
      const u16* sa2 = asrc + (t2 & 15) * 64;
      const u16* sb2 = bsrc + (size_t)(t2 >> 4) * 1048576 + (t2 & 15) * 64;
      GLL(sa2 + sgA[0], a2 + ldA[0]); GLL(sa2 + sgA[1], a2 + ldA[1]);
      GLL(sa2 + sgA[2], a2 + ldA[2]); GLL(sa2 + sgA[3], a2 + ldA[3]);
      GLL(sb2 + sgB[0], b2 + ldB[0]); GLL(sb2 + sgB[1], b2 + ldB[1]);
    }

    __builtin_amdgcn_s_setprio(1);
    #pragma unroll
    for (int mi = 0; mi < 8; ++mi) {
      acc[mi][0] = __builtin_amdgcn_mfma_f32_16x16x32_bf16(af[mi], bf0, acc[mi][0], 0, 0, 0);
      acc[mi][1] = __builtin_amdgcn_mfma_f32_16x16x32_bf16(af[mi], bf1, acc[mi][1], 0, 0, 0);
    }
    __builtin_amdgcn_s_setprio(0);

    // ---- kk = 1 ----
    #pragma unroll
    for (int mi = 0; mi < 8; ++mi) af[mi] = *(const bf16x8*)&a0[ra[mi] + pk1];
    bf0 = *(const bf16x8*)&b0[rb[0] + pk1];
    bf1 = *(const bf16x8*)&b0[rb[1] + pk1];

    __builtin_amdgcn_s_setprio(1);
    #pragma unroll
    for (int mi = 0; mi < 8; ++mi) {
      acc[mi][0] = __builtin_amdgcn_mfma_f32_16x16x32_bf16(af[mi], bf0, acc[mi][0], 0, 0, 0);
      acc[mi][1] = __builtin_amdgcn_mfma_f32_16x16x32_bf16(af[mi], bf1, acc[mi][1], 0, 0, 0);
    }
    __builtin_amdgcn_s_setprio(0);

    // expert boundary: relu + bias + gate into running oacc
    if ((t & 15) == 15) {
      int ml = t >> 4;
      float bvv[2];
      #pragma unroll
      for (int ni = 0; ni < 2; ++ni) bvv[ni] = lbias[ml * 128 + wn * 32 + ni * 16 + lrow];
      #pragma unroll
      for (int mi = 0; mi < 8; ++mi) {
        f32x4 gv = *(const f32x4*)&lgat[ml * 256 + wm * 128 + mi * 16 + lk * 4];
        #pragma unroll
        for (int ni = 0; ni < 2; ++ni) {
          #pragma unroll
          for (int j = 0; j < 4; ++j) {
            float h = acc[mi][ni][j] + bvv[ni];
            h = fmaxf(h, 0.f);
            oacc[mi][ni][j] += gv[j] * h;
          }
          acc[mi][ni] = zero4();
        }
      }
    }

    // counted vmcnt: drain t+1's 6 GLLs, keep t+2's 6 in flight
    if (t < NT - 2)       asm volatile("s_waitcnt vmcnt(6)" ::: "memory");
    else if (t == NT - 2) asm volatile("s_waitcnt vmcnt(0)" ::: "memory");
    if (t < NT - 1) {
      __builtin_amdgcn_s_barrier();
      __builtin_amdgcn_sched_barrier(0);
      u16* ta = a0; a0 = a1; a1 = a2; a2 = ta;
      u16* tb = b0; b0 = b1; b1 = b2; b2 = tb;
    }
  }

  float* op = grp ? p1out : out0;
  #pragma unroll
  for (int mi = 0; mi < 8; ++mi)
    #pragma unroll
    for (int j = 0; j < 4; ++j) {
      int row = brow0 + wm * 128 + mi * 16 + lk * 4 + j;
      #pragma unroll
      for (int ni = 0; ni < 2; ++ni) {
        int col = ncol0 + wn * 32 + ni * 16 + lrow;
        op[(size_t)row * 1024 + col] = oacc[mi][ni][j];
      }
    }
}

// ---- kernel 5: out += p1 ----
__global__ __launch_bounds__(256) void k_add(float* __restrict__ out, const float* __restrict__ p1) {
  int i = blockIdx.x * 256 + threadIdx.x;
  f32x4 a = ((const f32x4*)out)[i];
  f32x4 b = ((const f32x4*)p1)[i];
  ((f32x4*)out)[i] = a + b;
}

extern "C" void kernel_launch(void* const* d_in, const int* in_sizes, int n_in,
                              void* d_out, int out_size, void* d_ws, size_t ws_size,
                              hipStream_t stream) {
  const float* x  = (const float*)d_in[0];   // [4096][1024]
  const float* W  = (const float*)d_in[1];   // [16][1024][1024]
  const float* b  = (const float*)d_in[2];   // [16][1024]
  const float* Wg = (const float*)d_in[3];   // [1024][16]
  const float* bg = (const float*)d_in[4];   // [16]
  float* out = (float*)d_out;                // [4096][1024]

  char* ws = (char*)d_ws;
  u16* xb     = (u16*)ws;                      // 8,388,608 B (row-major bf16)
  u16* wt     = (u16*)(ws + 8388608);          // 33,554,432 B
  float* gts  = (float*)(ws + 41943040);       // 262,144 B
  float* p1   = (float*)(ws + 42205184);       // 16,777,216 B

  k_cvt_x<<<4096, 256, 0, stream>>>(x, xb);
  k_tw<<<4096, 256, 0, stream>>>(W, wt);
  k_gates<<<1024, 256, 0, stream>>>(x, Wg, bg, gts);
  k_moe<<<256, 512, 0, stream>>>(xb, wt, gts, b, out, p1);
  k_add<<<4096, 256, 0, stream>>>(out, p1);
}